// Round 3
// baseline (271.167 us; speedup 1.0000x reference)
//
#include <hip/hip_runtime.h>

// Problem: B=32, T=256, D=64
//   out[0, t, b, p, q] = r_p*r_q + i_p*i_q   (real part)
//   out[1, t, b, p, q] = i_p*r_q - r_p*i_q   (imag part)
// r[p] = real[b, t, p], i[p] = imag[b, t, p].
//
// Write-BW-bound: 268 MB output vs 4 MB input. Floor ≈ 41 µs at 6.6 TB/s.
// R2 design (= R1 with compile fix): one WAVE per (t,b) pair, no barriers.
//  - lane holds rv=r[lane], iv=i[lane] (registers)
//  - lane holds its q-slice float4 rq=r[4j..4j+3], j=lane&15 (L1 broadcast load)
//  - per-row scalars r_p, i_p via __shfl (ds_bpermute), 2 per iteration
//  - 32 nontemporal dwordx4 stores per wave, issued back-to-back
//  - nontemporal stores use native ext_vector_type (HIP float4 struct is
//    rejected by __builtin_nontemporal_store)

typedef float v4f __attribute__((ext_vector_type(4)));

namespace {
constexpr int kB = 32;
constexpr int kT = 256;
constexpr int kD = 64;
constexpr int kDD = kD * kD;                 // 4096 floats per pair per part
constexpr int kPairs = kT * kB;              // 8192
}

__global__ __launch_bounds__(256) void qouter_kernel(
    const float* __restrict__ real,
    const float* __restrict__ imag,
    float* __restrict__ out) {
    const int lane = threadIdx.x & 63;
    const int wavesPerBlock = blockDim.x >> 6;
    const int wid = blockIdx.x * wavesPerBlock + (threadIdx.x >> 6);
    const int nwaves = gridDim.x * wavesPerBlock;

    for (int pair = wid; pair < kPairs; pair += nwaves) {
        const int t = pair >> 5;             // pair / kB
        const int b = pair & (kB - 1);       // pair % kB
        const int in_base = (b * kT + t) * kD;

        // per-lane register copies
        const float rv = real[in_base + lane];
        const float iv = imag[in_base + lane];
        const int j = lane & 15;
        const v4f rq = *(const v4f*)(real + in_base + 4 * j);
        const v4f iq = *(const v4f*)(imag + in_base + 4 * j);

        v4f* __restrict__ outr = (v4f*)(out + (size_t)pair * kDD);
        v4f* __restrict__ outi = (v4f*)(out + (size_t)pair * kDD
                                        + (size_t)kPairs * kDD);

#pragma unroll
        for (int it = 0; it < 16; ++it) {
            const int idx = it * 64 + lane;  // float4 index within pair, 0..1023
            const int p = idx >> 4;          // output row
            const float rp = __shfl(rv, p);
            const float ip = __shfl(iv, p);
            v4f vr, vi;
            vr.x = rp * rq.x + ip * iq.x;
            vr.y = rp * rq.y + ip * iq.y;
            vr.z = rp * rq.z + ip * iq.z;
            vr.w = rp * rq.w + ip * iq.w;
            vi.x = ip * rq.x - rp * iq.x;
            vi.y = ip * rq.y - rp * iq.y;
            vi.z = ip * rq.z - rp * iq.z;
            vi.w = ip * rq.w - rp * iq.w;
            __builtin_nontemporal_store(vr, outr + idx);
            __builtin_nontemporal_store(vi, outi + idx);
        }
    }
}

extern "C" void kernel_launch(void* const* d_in, const int* in_sizes, int n_in,
                              void* d_out, int out_size, void* d_ws, size_t ws_size,
                              hipStream_t stream) {
    const float* real = (const float*)d_in[0];
    const float* imag = (const float*)d_in[1];
    float* out = (float*)d_out;
    // 2048 blocks x 256 threads = 8192 waves = one wave per pair
    qouter_kernel<<<2048, 256, 0, stream>>>(real, imag, out);
}

// Round 4
// 267.475 us; speedup vs baseline: 1.0138x; 1.0138x over previous
//
#include <hip/hip_runtime.h>

// Problem: B=32, T=256, D=64
//   out[0, t, b, p, q] = r_p*r_q + i_p*i_q   (real part)
//   out[1, t, b, p, q] = i_p*r_q - r_p*i_q   (imag part)
// r[p] = real[b, t, p], i[p] = imag[b, t, p].
//
// Write-BW-bound: 268 MB output vs 4 MB input. Floor ≈ 41 µs at 6.5 TB/s.
// R3 design: one WAVE per (pair, part) — 16384 waves, each writes ONE
// contiguous 16 KB stream (single-stream stores, no interleave).
//  - lane holds rv=r[lane], iv=i[lane] (registers)
//  - lane holds q-slice float4 rq/iq (j=lane&15, L1 broadcast load)
//  - per-row scalars via __shfl; part-dependent sign via wave-uniform selects
//  - nontemporal dwordx4 stores, fully unrolled, back-to-back

typedef float v4f __attribute__((ext_vector_type(4)));

namespace {
constexpr int kB = 32;
constexpr int kT = 256;
constexpr int kD = 64;
constexpr int kDD = kD * kD;                 // 4096 floats per pair per part
constexpr int kPairs = kT * kB;              // 8192
}

__global__ __launch_bounds__(256) void qouter_kernel(
    const float* __restrict__ real,
    const float* __restrict__ imag,
    float* __restrict__ out) {
    const int lane = threadIdx.x & 63;
    const int wid = blockIdx.x * 4 + (threadIdx.x >> 6);   // 0 .. 16383
    const int part = wid >> 13;                            // 0: real, 1: imag
    const int pair = wid & (kPairs - 1);
    const int t = pair >> 5;                               // pair / kB
    const int b = pair & (kB - 1);                         // pair % kB
    const int in_base = (b * kT + t) * kD;

    const float rv = real[in_base + lane];
    const float iv = imag[in_base + lane];
    const int j = lane & 15;
    const v4f rq = *(const v4f*)(real + in_base + 4 * j);
    const v4f iq = *(const v4f*)(imag + in_base + 4 * j);
    const bool isImag = (part != 0);

    v4f* __restrict__ outp = (v4f*)(out + ((size_t)part * kPairs + pair) * kDD);

#pragma unroll
    for (int it = 0; it < 16; ++it) {
        const int idx = it * 64 + lane;      // float4 index within part, 0..1023
        const int p = idx >> 4;              // output row
        const float rp = __shfl(rv, p);
        const float ip = __shfl(iv, p);
        // real part: rp*rq + ip*iq ; imag part: ip*rq - rp*iq
        const float a1 = isImag ? ip : rp;
        const float a2 = isImag ? -rp : ip;
        v4f v;
        v.x = a1 * rq.x + a2 * iq.x;
        v.y = a1 * rq.y + a2 * iq.y;
        v.z = a1 * rq.z + a2 * iq.z;
        v.w = a1 * rq.w + a2 * iq.w;
        __builtin_nontemporal_store(v, outp + idx);
    }
}

extern "C" void kernel_launch(void* const* d_in, const int* in_sizes, int n_in,
                              void* d_out, int out_size, void* d_ws, size_t ws_size,
                              hipStream_t stream) {
    const float* real = (const float*)d_in[0];
    const float* imag = (const float*)d_in[1];
    float* out = (float*)d_out;
    // 4096 blocks x 256 threads = 16384 waves = one wave per (pair, part)
    qouter_kernel<<<4096, 256, 0, stream>>>(real, imag, out);
}